// Round 7
// baseline (246.913 us; speedup 1.0000x reference)
//
#include <hip/hip_runtime.h>
#include <math.h>

#define BB 1024
#define SS 50
#define HH 128
#define KK 4
#define VV 100000
#define NVT 782         // ceil(V/128)
#define NVT8 784        // padded to multiple of 8 for XCD swizzle
#define VPAD (NVT8*128) // 100352 zero-padded emb rows
#define KS (KK*SS)      // 200
#define NCONV ((VPAD*HH)/1024)  // 12544 conversion blocks
#define NH ((BB*SS)/64)         // 800 h-GEMM blocks
#define NPAD_LAST 96.0f // pad rows in tile 781, each contributes exp(0)=1

typedef __attribute__((ext_vector_type(8))) short bf16x8;
typedef __attribute__((ext_vector_type(4))) float f32x4;

__device__ __forceinline__ ushort f2bf(float x) {
  unsigned u = __float_as_uint(x);
  unsigned r = u + 0x7FFF + ((u >> 16) & 1);   // round-to-nearest-even
  return (ushort)(r >> 16);
}
__device__ __forceinline__ float bf2f(ushort u) {
  return __uint_as_float(((unsigned)u) << 16);
}

// ---- fused pre-pass:  blocks [0,NCONV): emb->bf16 (padded)
//                       blocks [NCONV,NCONV+KS): cw0 column exp-sums + zero bufs
//                       blocks [NCONV+KS, +NH): h = seq_emb @ W^T  -> bf16
__global__ __launch_bounds__(256) void k_pre(const float* __restrict__ emb,
                                             ushort* __restrict__ embb,
                                             const float* __restrict__ cw0,
                                             float* __restrict__ cm,
                                             float* __restrict__ s1,
                                             float* __restrict__ s2,
                                             float* __restrict__ accum,
                                             const int* __restrict__ item_seq,
                                             const float* __restrict__ W,
                                             ushort* __restrict__ hb16) {
  const int t = threadIdx.x;
  if (blockIdx.x < NCONV) {
    size_t i = ((size_t)blockIdx.x * 256 + t) * 4;
    ushort4 o;
    if (i < (size_t)VV * HH) {
      float4 v = *(const float4*)&emb[i];
      o = make_ushort4(f2bf(v.x), f2bf(v.y), f2bf(v.z), f2bf(v.w));
    } else {
      o = make_ushort4(0, 0, 0, 0);
    }
    *(ushort4*)&embb[i] = o;
  } else if (blockIdx.x < NCONV + KS) {
    __shared__ float red[256];
    const int c = blockIdx.x - NCONV;
    if (t < 8) s1[t * KS + c] = 0.f;
    else if (t < 16) s2[(t - 8) * KS + c] = 0.f;
    if (c < 4) accum[c * 256 + t] = 0.f;
    float s = 0.f;
    for (int b = t; b < BB; b += 256) s += __expf(cw0[(size_t)b * KS + c]);
    red[t] = s;
    __syncthreads();
    for (int o = 128; o > 0; o >>= 1) {
      if (t < o) red[t] += red[t + o];
      __syncthreads();
    }
    if (t == 0) cm[c] = red[0];
  } else {
    // ---- h GEMM block ----
    __shared__ float sAT[64][65];
    __shared__ float sW[128][68];
    const int mq = t & 15;
    const int nq = t >> 4;
    const int rbase = (blockIdx.x - NCONV - KS) * 64;

    float acc[4][8];
#pragma unroll
    for (int i = 0; i < 4; ++i)
#pragma unroll
      for (int j = 0; j < 8; ++j) acc[i][j] = 0.f;

    for (int kk = 0; kk < 128; kk += 64) {
#pragma unroll
      for (int it = 0; it < 4; ++it) {
        int pos = t + it * 256;
        int m = pos >> 4, c4 = pos & 15;
        int idx = item_seq[rbase + m];
        float4 v = make_float4(0.f, 0.f, 0.f, 0.f);
        if (idx != 0) v = *(const float4*)&emb[(size_t)idx * HH + kk + 4 * c4];
        sAT[4 * c4 + 0][m] = v.x;
        sAT[4 * c4 + 1][m] = v.y;
        sAT[4 * c4 + 2][m] = v.z;
        sAT[4 * c4 + 3][m] = v.w;
      }
#pragma unroll
      for (int it = 0; it < 8; ++it) {
        int pos = t + it * 256;
        int n = pos >> 4, c4 = pos & 15;
        *(float4*)&sW[n][4 * c4] = *(const float4*)&W[n * HH + kk + 4 * c4];
      }
      __syncthreads();

      for (int k = 0; k < 64; k += 4) {
        float a[4][4];
#pragma unroll
        for (int kc = 0; kc < 4; ++kc)
#pragma unroll
          for (int i = 0; i < 4; ++i) a[i][kc] = sAT[k + kc][4 * mq + i];
#pragma unroll
        for (int j = 0; j < 8; ++j) {
          float4 w4 = *(const float4*)&sW[nq + 16 * j][k];
          float w[4] = {w4.x, w4.y, w4.z, w4.w};
#pragma unroll
          for (int i = 0; i < 4; ++i)
#pragma unroll
            for (int kc = 0; kc < 4; ++kc) acc[i][j] += a[i][kc] * w[kc];
        }
      }
      __syncthreads();
    }
#pragma unroll
    for (int i = 0; i < 4; ++i)
#pragma unroll
      for (int j = 0; j < 8; ++j)
        hb16[(size_t)(rbase + 4 * mq + i) * HH + nq + 16 * j] = f2bf(acc[i][j]);
  }
}

// ---------------- routing: per-batch step (h in bf16) ---------------------
__global__ __launch_bounds__(256) void k_route(const float* __restrict__ cwsrc,
                                               float* __restrict__ cwdst,
                                               const ushort* __restrict__ hbuf,
                                               const float* __restrict__ csum,
                                               int nslots,
                                               const float* __restrict__ mask,
                                               int last,
                                               float* __restrict__ out_ue,
                                               const float* __restrict__ emb,
                                               const int* __restrict__ item,
                                               ushort* __restrict__ bestb,
                                               float* __restrict__ csnext,
                                               float* __restrict__ si) {
  __shared__ __align__(16) float sw[KS];
  __shared__ __align__(16) float c32p[256];
  __shared__ __align__(16) float c32[128];
  __shared__ __align__(16) float csq[128];
  __shared__ __align__(16) float ie4r[32];
  __shared__ __align__(16) float ie4z[32];
  __shared__ float fac[4];
  __shared__ float cosk[4];
  __shared__ float cosr[4];
  __shared__ int kb;
  const int t = threadIdx.x;
  const int b = blockIdx.x;
  const ushort* hb = hbuf + (size_t)b * (SS * HH);

  if (t < KS) {
    int s = t % SS;
    float den = 0.f;
    for (int g2 = 0; g2 < nslots; ++g2) den += csum[g2 * KS + t];
    float v = __expf(cwsrc[(size_t)b * KS + t]) / den;
    if (mask[b * SS + s] == 0.0f) v = 0.0f;
    sw[t] = v;
  }
  __syncthreads();

  {  // c32 with all 256 threads: col = t&127, s-half = t>>7 (25 each)
    int col = t & 127;
    int half = t >> 7;
    int k = col >> 5;
    float acc = 0.f;
    const float* swk = &sw[k * SS + half * 25];
    const ushort* hc = hb + (size_t)(half * 25) * HH + col;
    for (int s = 0; s < 25; ++s) acc += swk[s] * bf2f(hc[(size_t)s * HH]);
    c32p[t] = acc;
  }
  __syncthreads();
  if (t < 128) c32[t] = c32p[t] + c32p[t + 128];
  __syncthreads();

  if (t < 4) {
    float nrm = 0.f;
#pragma unroll
    for (int j = 0; j < 32; ++j) { float c = c32[32 * t + j]; nrm += c * c; }
    nrm *= 4.0f;
    fac[t] = nrm / (1.0f + nrm) / sqrtf(nrm + 1e-9f);
  }
  __syncthreads();
  if (t < 128) csq[t] = c32[t] * fac[t >> 5];
  __syncthreads();

  if (!last) {
    if (t < KS) {
      int k = t / SS, s = t % SS;
      const ushort* hrow = hb + (size_t)s * HH + 32 * k;
      const float* cq = &csq[32 * k];
      float d = 0.f;
#pragma unroll
      for (int j = 0; j < 4; ++j) {
        uint4 pk = *(const uint4*)&hrow[8 * j];
        d += __uint_as_float(pk.x << 16)          * cq[8 * j + 0];
        d += __uint_as_float(pk.x & 0xFFFF0000u)  * cq[8 * j + 1];
        d += __uint_as_float(pk.y << 16)          * cq[8 * j + 2];
        d += __uint_as_float(pk.y & 0xFFFF0000u)  * cq[8 * j + 3];
        d += __uint_as_float(pk.z << 16)          * cq[8 * j + 4];
        d += __uint_as_float(pk.z & 0xFFFF0000u)  * cq[8 * j + 5];
        d += __uint_as_float(pk.w << 16)          * cq[8 * j + 6];
        d += __uint_as_float(pk.w & 0xFFFF0000u)  * cq[8 * j + 7];
      }
      float nv = cwsrc[(size_t)b * KS + t] + 4.0f * d;
      cwdst[(size_t)b * KS + t] = nv;
      atomicAdd(&csnext[(b & 7) * KS + t], __expf(nv));
    }
  } else {
    for (int hh = t; hh < 512; hh += 256) {
      int k = hh >> 7, r = (hh & 127) >> 2;
      out_ue[(size_t)b * 512 + hh] = csq[32 * k + r];
    }
    if (t < 32) {
      int idx = item[b];
      const float* e = emb + (size_t)idx * HH + 4 * t;
      float v = e[0] + e[1] + e[2] + e[3];   // raw emb row (scores use raw emb)
      ie4r[t] = v;
      ie4z[t] = (idx == 0) ? 0.f : v;        // zeroed lookup (cos path)
    }
    __syncthreads();
    if (t < 4) {
      float cz = 0.f, cr = 0.f;
#pragma unroll
      for (int j = 0; j < 32; ++j) {
        cz += csq[32 * t + j] * ie4z[j];
        cr += csq[32 * t + j] * ie4r[j];
      }
      cosk[t] = cz; cosr[t] = cr;
    }
    __syncthreads();
    if (t == 0) {
      int kbest = 0; float bv = cosk[0];
#pragma unroll
      for (int k = 1; k < 4; ++k) if (cosk[k] > bv) { bv = cosk[k]; kbest = k; }
      kb = kbest;
      si[b] = cosr[kbest];
    }
    __syncthreads();
    if (t < 128) bestb[(size_t)b * HH + t] = f2bf(csq[32 * kb + (t >> 2)]);
  }
}

// ---------------- scoring: MFMA bf16 GEMM + fused sum-of-exp --------------
// 64b x 128v per block (16 KB LDS, half the register footprint, 49 blocks/CU)
// bt-interleaved epilogue: bt+1's MFMAs co-issue with bt's exps.
// Partial sums go straight into per-b atomic accumulators (no ps buffer).
__global__ __launch_bounds__(256) void k_score_mfma(const ushort* __restrict__ bestb,
                                                    const ushort* __restrict__ embb,
                                                    float* __restrict__ accum) {
  const int lin = blockIdx.x;
  const int xcd = lin & 7;
  const int g = lin >> 3;
  const int btile = g & 15;
  const int vt = xcd * (NVT8 / 8) + (g >> 4);
  if (vt >= NVT) return;   // uniform across block: safe

  __shared__ __align__(16) ushort sB[16 * 512];   // 16 KB
  __shared__ float ssm[64][4];
  const int t = threadIdx.x;
  const int w = t >> 6;
  const int lane = t & 63;
  const int lr = lane & 15;
  const int lq = lane >> 4;
  const int b0 = btile * 64;
  const int v0 = vt * 128 + w * 32;

  // emb fragments (per-wave unique), hoisted: 32 VGPRs in flight
  bf16x8 af[4][2];
#pragma unroll
  for (int ks = 0; ks < 4; ++ks)
#pragma unroll
    for (int vv = 0; vv < 2; ++vv)
      af[ks][vv] = *(const bf16x8*)&embb[(size_t)(v0 + vv * 16 + lr) * HH + ks * 32 + lq * 8];

  // stage bestb strip (fragment order: chunk ks*4+bt = 64 lanes x 16 B)
#pragma unroll
  for (int it = 0; it < 4; ++it) {
    int pos = t + it * 256;          // 0..1023
    int ch = pos >> 6;               // 0..15
    int l = pos & 63;
    int ks = ch >> 2, bt = ch & 3;
    *(bf16x8*)&sB[ch * 512 + l * 8] =
        *(const bf16x8*)&bestb[(size_t)(b0 + bt * 16 + (l & 15)) * HH + ks * 32 + (l >> 4) * 8];
  }
  __syncthreads();

#pragma unroll
  for (int bt = 0; bt < 4; ++bt) {
    bf16x8 bfr[4];
#pragma unroll
    for (int ks = 0; ks < 4; ++ks)
      bfr[ks] = *(const bf16x8*)&sB[(ks * 4 + bt) * 512 + lane * 8];
    f32x4 a0 = (f32x4){0.f, 0.f, 0.f, 0.f};
    f32x4 a1 = (f32x4){0.f, 0.f, 0.f, 0.f};
#pragma unroll
    for (int ks = 0; ks < 4; ++ks) {
      a0 = __builtin_amdgcn_mfma_f32_16x16x32_bf16(af[ks][0], bfr[ks], a0, 0, 0, 0);
      a1 = __builtin_amdgcn_mfma_f32_16x16x32_bf16(af[ks][1], bfr[ks], a1, 0, 0, 0);
    }
    float s = 0.f;
#pragma unroll
    for (int r = 0; r < 4; ++r) s += __expf(a0[r]) + __expf(a1[r]);
    s += __shfl_xor(s, 16);
    s += __shfl_xor(s, 32);
    if (lq == 0) ssm[bt * 16 + lr][w] = s;
  }
  __syncthreads();
  if (t < 64) {
    float s = ssm[t][0] + ssm[t][1] + ssm[t][2] + ssm[t][3];
    atomicAdd(&accum[b0 + t], s);
  }
}

// ---------------- final loss: one block -----------------------------------
__global__ __launch_bounds__(256) void k_loss(const float* __restrict__ accum,
                                              const float* __restrict__ si,
                                              float* __restrict__ outloss) {
  __shared__ float red[256];
  const int t = threadIdx.x;
  float s = 0.f;
  for (int b = t; b < BB; b += 256)
    s += logf(accum[b] - NPAD_LAST) - si[b];   // no max: scores ~[-0.5,0.5]
  red[t] = s;
  __syncthreads();
  for (int o = 128; o > 0; o >>= 1) {
    if (t < o) red[t] += red[t + o];
    __syncthreads();
  }
  if (t == 0) outloss[0] = red[0] / (float)BB;
}

extern "C" void kernel_launch(void* const* d_in, const int* in_sizes, int n_in,
                              void* d_out, int out_size, void* d_ws, size_t ws_size,
                              hipStream_t stream) {
  const int*   item_seq = (const int*)d_in[0];
  const float* mask     = (const float*)d_in[1];
  const int*   item     = (const int*)d_in[2];
  const float* emb      = (const float*)d_in[3];
  const float* W        = (const float*)d_in[4];
  const float* cw0      = (const float*)d_in[5];
  float* out = (float*)d_out;
  float* outloss = out + (size_t)BB * KK * HH;

  float* ws = (float*)d_ws;
  float* cw    = ws;                                 // B*K*S
  float* cm    = cw + (size_t)BB * KS;               // 256 (uses KS=200)
  float* s1    = cm + 256;                           // 8*200
  float* s2    = s1 + 8 * KS;                        // 8*200
  float* si    = s2 + 8 * KS;                        // B
  float* accum = si + BB;                            // B
  ushort* hb16  = (ushort*)(accum + BB);             // B*S*H bf16
  ushort* embb  = hb16 + (size_t)BB * SS * HH;       // VPAD*H bf16
  ushort* bestb = embb + (size_t)VPAD * HH;          // B*H bf16

  k_pre<<<dim3(NCONV + KS + NH), 256, 0, stream>>>(emb, embb, cw0, cm, s1, s2,
                                                   accum, item_seq, W, hb16);

  k_route<<<dim3(BB), 256, 0, stream>>>(cw0, cw, hb16, cm, 1, mask, 0, out, emb, item, bestb, s1, si);
  k_route<<<dim3(BB), 256, 0, stream>>>(cw, cw, hb16, s1, 8, mask, 0, out, emb, item, bestb, s2, si);
  k_route<<<dim3(BB), 256, 0, stream>>>(cw, cw, hb16, s2, 8, mask, 1, out, emb, item, bestb, s1, si);

  k_score_mfma<<<dim3(NVT8 * 16), 256, 0, stream>>>(bestb, embb, accum);
  k_loss<<<dim3(1), 256, 0, stream>>>(accum, si, outloss);
}